// Round 4
// baseline (686.125 us; speedup 1.0000x reference)
//
#include <hip/hip_runtime.h>
#include <cstdint>
#include <cstddef>

typedef _Float16 half_t;
typedef _Float16 half8 __attribute__((ext_vector_type(8)));
typedef float floatx4 __attribute__((ext_vector_type(4)));

#define E_ 8
#define D_ 512
#define H_ 2048
#define NTOK 1024
#define NP 2048            // NTOK * top_k
#define TM 64              // GEMM M-tile rows
#define MAX_TILES 40       // 2048/64 + 8 experts
#define NBLK 512
#define NJ1 (MAX_TILES * (H_ / 64))   // 1280 gemm1 jobs (t, cb)
#define NJ2 (MAX_TILES * 8 * 4)       // 1280 gemm2 jobs (t, cb, kz)

// ---- grid barrier state in device globals (NOT in poisoned workspace) ----
__device__ int g_bar_cnt = 0;
__device__ int g_bar_gen = 0;

__device__ __forceinline__ void grid_sync() {
    __syncthreads();
    if (threadIdx.x == 0) {
        __threadfence();   // agent-scope: make this block's writes visible
        int g = __hip_atomic_load(&g_bar_gen, __ATOMIC_RELAXED, __HIP_MEMORY_SCOPE_AGENT);
        int a = __hip_atomic_fetch_add(&g_bar_cnt, 1, __ATOMIC_ACQ_REL, __HIP_MEMORY_SCOPE_AGENT);
        if (a == NBLK - 1) {
            __hip_atomic_store(&g_bar_cnt, 0, __ATOMIC_RELAXED, __HIP_MEMORY_SCOPE_AGENT);
            __hip_atomic_fetch_add(&g_bar_gen, 1, __ATOMIC_RELEASE, __HIP_MEMORY_SCOPE_AGENT);
        } else {
            while (__hip_atomic_load(&g_bar_gen, __ATOMIC_ACQUIRE, __HIP_MEMORY_SCOPE_AGENT) == g)
                __builtin_amdgcn_s_sleep(2);
        }
        __threadfence();
    }
    __syncthreads();
}

__device__ __forceinline__ float gelu_f(float x) {
    return 0.5f * x * (1.0f + erff(x * 0.7071067811865476f));
}

__device__ __forceinline__ half8 cvt8(floatx4 a, floatx4 b) {
    half8 h = { (half_t)a[0], (half_t)a[1], (half_t)a[2], (half_t)a[3],
                (half_t)b[0], (half_t)b[1], (half_t)b[2], (half_t)b[3] };
    return h;
}

struct KP {
    const float* inp; const float* gate_w; const float* gate_b;
    const float* w1; const float* b1; const float* w2; const float* b2;
    const float* ln_w; const float* ln_b; float* out;
    half_t* Y1; float* Y2p; float* logits; float* score;
    int* idx; int* pos_of_pair; int* tok_of_pos;
    int* tile_e; int* tile_row0; int* tile_cnt; int* ntiles;
};

__global__ __launch_bounds__(256, 2) void moe_kernel(KP p) {
    __shared__ half_t As[2][64 * 64];   // 16 KB
    __shared__ half_t Bs[2][64 * 64];   // 16 KB
    __shared__ int cnt_s[E_], off_s[E_ + 1], cur_s[E_];
    const int bid = blockIdx.x, tid = threadIdx.x;
    const int wave = tid >> 6, lane = tid & 63;
    const int quad = lane >> 4, l16 = lane & 15;

    // ================= P0: gate logits (wave per token) =================
    {
        int wid = bid * 4 + wave;
        if (wid < NTOK) {
            int n = wid;
            const floatx4* xr = (const floatx4*)(p.inp + (size_t)n * D_);
            floatx4 x0 = xr[lane * 2], x1 = xr[lane * 2 + 1];
            #pragma unroll
            for (int e = 0; e < E_; e++) {
                const floatx4* gr = (const floatx4*)(p.gate_w + (size_t)e * D_);
                floatx4 g0 = gr[lane * 2], g1 = gr[lane * 2 + 1];
                float v = x0[0]*g0[0] + x0[1]*g0[1] + x0[2]*g0[2] + x0[3]*g0[3]
                        + x1[0]*g1[0] + x1[1]*g1[1] + x1[2]*g1[2] + x1[3]*g1[3];
                #pragma unroll
                for (int m = 1; m < 64; m <<= 1) v += __shfl_xor(v, m);
                if (lane == 0) p.logits[(size_t)n * E_ + e] = v + p.gate_b[e];
            }
        }
    }
    grid_sync();

    // ================= P1: plan (block 0 only) =================
    if (bid == 0) {
        if (tid < E_) { cnt_s[tid] = 0; cur_s[tid] = 0; }
        __syncthreads();
        int my_e[4][2];
        #pragma unroll
        for (int i = 0; i < 4; i++) {
            int n = tid + i * 256;
            float l[E_];
            #pragma unroll
            for (int e = 0; e < E_; e++) l[e] = p.logits[(size_t)n * E_ + e];
            int e0 = 0; float v0 = l[0];
            #pragma unroll
            for (int e = 1; e < E_; e++) if (l[e] > v0) { v0 = l[e]; e0 = e; }
            int e1 = -1; float v1 = -3.4e38f;
            #pragma unroll
            for (int e = 0; e < E_; e++) if (e != e0 && l[e] > v1) { v1 = l[e]; e1 = e; }
            float s1 = expf(v1 - v0);
            float den = 1.0f + s1;
            p.score[2 * n]     = 1.0f / den;
            p.score[2 * n + 1] = s1 / den;
            p.idx[2 * n]     = e0;
            p.idx[2 * n + 1] = e1;
            atomicAdd(&cnt_s[e0], 1);
            atomicAdd(&cnt_s[e1], 1);
            my_e[i][0] = e0; my_e[i][1] = e1;
        }
        __syncthreads();
        if (tid == 0) {
            int o = 0;
            #pragma unroll
            for (int e = 0; e < E_; e++) { off_s[e] = o; o += cnt_s[e]; }
            off_s[E_] = o;
            int t = 0;
            for (int e = 0; e < E_; e++) {
                int c = cnt_s[e];
                int nt = (c + TM - 1) / TM;
                for (int i = 0; i < nt; i++) {
                    p.tile_e[t] = e;
                    p.tile_row0[t] = off_s[e] + i * TM;
                    int rem = c - i * TM;
                    p.tile_cnt[t] = rem < TM ? rem : TM;
                    t++;
                }
            }
            p.ntiles[0] = t;
        }
        __syncthreads();
        #pragma unroll
        for (int i = 0; i < 4; i++) {
            #pragma unroll
            for (int k = 0; k < 2; k++) {
                int pp = (tid + i * 256) * 2 + k;
                int e = my_e[i][k];
                int r = atomicAdd(&cur_s[e], 1);
                int pos = off_s[e] + r;
                p.pos_of_pair[pp] = pos;
                p.tok_of_pos[pos] = pp >> 1;
            }
        }
    }
    grid_sync();

    // shared geometry for the GEMM phases
    const int wm = (wave & 1) * 32, wn = (wave >> 1) * 32;
    const int xm = l16 & 7;
    const int gr0 = tid >> 3, gr1 = gr0 + 32, gc = tid & 7;
    const int sw0 = gc ^ (gr0 & 7), sw1 = gc ^ (gr1 & 7);
    const int sa0 = gr0 * 64 + sw0 * 8, sa1 = gr1 * 64 + sw1 * 8;
    const int xcd = bid & 7, ib = bid >> 3;       // 64 blocks per XCD chunk

    // ================= P2: gemm1  Y1 = gelu(inp[tok] @ W1[e]^T + b1) =================
    {
        const int nt = p.ntiles[0];
        const int CH = NJ1 / 8;                    // 160 jobs per XCD chunk
        for (int j = xcd * CH + ib; j < (xcd + 1) * CH; j += NBLK / 8) {
            int t = j % MAX_TILES, cb = j / MAX_TILES;
            if (t >= nt) continue;
            int e = p.tile_e[t], row0 = p.tile_row0[t], cnt = p.tile_cnt[t];
            int colbase = cb * 64;
            int ar0 = row0 + gr0; if (ar0 > NP - 1) ar0 = NP - 1;
            int ar1 = row0 + gr1; if (ar1 > NP - 1) ar1 = NP - 1;
            int tok0 = p.tok_of_pos[ar0];
            int tok1 = p.tok_of_pos[ar1];
            const floatx4* Ag0 = (const floatx4*)(p.inp + (size_t)tok0 * D_) + gc * 2;
            const floatx4* Ag1 = (const floatx4*)(p.inp + (size_t)tok1 * D_) + gc * 2;
            const floatx4* Bg0 = (const floatx4*)(p.w1 + ((size_t)e * H_ + colbase + gr0) * D_) + gc * 2;
            const floatx4* Bg1 = (const floatx4*)(p.w1 + ((size_t)e * H_ + colbase + gr1) * D_) + gc * 2;

            floatx4 ra0a, ra0b, ra1a, ra1b, rb0a, rb0b, rb1a, rb1b;
            #define LOAD1(kq) do { \
                ra0a = Ag0[kq]; ra0b = Ag0[(kq) + 1]; \
                ra1a = Ag1[kq]; ra1b = Ag1[(kq) + 1]; \
                rb0a = Bg0[kq]; rb0b = Bg0[(kq) + 1]; \
                rb1a = Bg1[kq]; rb1b = Bg1[(kq) + 1]; } while (0)
            #define CVW1(buf) do { \
                *(half8*)(&As[buf][sa0]) = cvt8(ra0a, ra0b); \
                *(half8*)(&As[buf][sa1]) = cvt8(ra1a, ra1b); \
                *(half8*)(&Bs[buf][sa0]) = cvt8(rb0a, rb0b); \
                *(half8*)(&Bs[buf][sa1]) = cvt8(rb1a, rb1b); } while (0)

            floatx4 acc[2][2] = {};
            LOAD1(0);
            CVW1(0);
            __syncthreads();
            int cur = 0;
            for (int k0 = 0; k0 < D_; k0 += 64) {
                bool more = (k0 + 64) < D_;
                if (more) LOAD1((k0 + 64) >> 2);
                const half_t* Ab = &As[cur][0];
                const half_t* Bb = &Bs[cur][0];
                #pragma unroll
                for (int ks = 0; ks < 2; ks++) {
                    half8 a[2], b[2];
                    #pragma unroll
                    for (int mi = 0; mi < 2; mi++)
                        a[mi] = *(const half8*)(Ab + (wm + mi * 16 + l16) * 64 + ((ks * 4 + quad) ^ xm) * 8);
                    #pragma unroll
                    for (int ni = 0; ni < 2; ni++)
                        b[ni] = *(const half8*)(Bb + (wn + ni * 16 + l16) * 64 + ((ks * 4 + quad) ^ xm) * 8);
                    #pragma unroll
                    for (int mi = 0; mi < 2; mi++)
                        #pragma unroll
                        for (int ni = 0; ni < 2; ni++)
                            acc[mi][ni] = __builtin_amdgcn_mfma_f32_16x16x32_f16(a[mi], b[ni], acc[mi][ni], 0, 0, 0);
                }
                if (more) CVW1(cur ^ 1);
                __syncthreads();
                cur ^= 1;
            }
            #undef LOAD1
            #undef CVW1

            float bias[2];
            #pragma unroll
            for (int ni = 0; ni < 2; ni++)
                bias[ni] = p.b1[(size_t)e * H_ + colbase + wn + ni * 16 + l16];
            #pragma unroll
            for (int mi = 0; mi < 2; mi++) {
                #pragma unroll
                for (int r = 0; r < 4; r++) {
                    int rr = wm + mi * 16 + quad * 4 + r;
                    if (rr >= cnt) continue;
                    size_t rowoff = (size_t)(row0 + rr) * H_;
                    #pragma unroll
                    for (int ni = 0; ni < 2; ni++) {
                        float v = acc[mi][ni][r] + bias[ni];
                        p.Y1[rowoff + colbase + wn + ni * 16 + l16] = (half_t)gelu_f(v);
                    }
                }
            }
        }
    }
    grid_sync();

    // ================= P3: gemm2 (split-K=4)  Y2p[kz] = Y1 @ W2[e]^T =================
    {
        const int nt = p.ntiles[0];
        const int CH = NJ2 / 8;                    // 160
        for (int j = xcd * CH + ib; j < (xcd + 1) * CH; j += NBLK / 8) {
            int t = j % MAX_TILES;
            int rest = j / MAX_TILES;
            int cb = rest & 7;
            int kz = rest >> 3;
            if (t >= nt) continue;
            int e = p.tile_e[t], row0 = p.tile_row0[t], cnt = p.tile_cnt[t];
            int colbase = cb * 64;
            int kzbase = kz * 512;
            const half8* Ag0 = (const half8*)(p.Y1 + (size_t)(row0 + gr0) * H_ + kzbase) + gc;
            const half8* Ag1 = (const half8*)(p.Y1 + (size_t)(row0 + gr1) * H_ + kzbase) + gc;
            const floatx4* Bg0 = (const floatx4*)(p.w2 + ((size_t)e * D_ + colbase + gr0) * H_ + kzbase) + gc * 2;
            const floatx4* Bg1 = (const floatx4*)(p.w2 + ((size_t)e * D_ + colbase + gr1) * H_ + kzbase) + gc * 2;

            half8 ha0, ha1;
            floatx4 rb0a, rb0b, rb1a, rb1b;
            #define LOAD2(k0) do { \
                ha0 = Ag0[(k0) >> 3]; ha1 = Ag1[(k0) >> 3]; \
                rb0a = Bg0[(k0) >> 2]; rb0b = Bg0[((k0) >> 2) + 1]; \
                rb1a = Bg1[(k0) >> 2]; rb1b = Bg1[((k0) >> 2) + 1]; } while (0)
            #define CVW2(buf) do { \
                *(half8*)(&As[buf][sa0]) = ha0; \
                *(half8*)(&As[buf][sa1]) = ha1; \
                *(half8*)(&Bs[buf][sa0]) = cvt8(rb0a, rb0b); \
                *(half8*)(&Bs[buf][sa1]) = cvt8(rb1a, rb1b); } while (0)

            floatx4 acc[2][2] = {};
            LOAD2(0);
            CVW2(0);
            __syncthreads();
            int cur = 0;
            for (int k0 = 0; k0 < 512; k0 += 64) {
                bool more = (k0 + 64) < 512;
                if (more) LOAD2(k0 + 64);
                const half_t* Ab = &As[cur][0];
                const half_t* Bb = &Bs[cur][0];
                #pragma unroll
                for (int ks = 0; ks < 2; ks++) {
                    half8 a[2], b[2];
                    #pragma unroll
                    for (int mi = 0; mi < 2; mi++)
                        a[mi] = *(const half8*)(Ab + (wm + mi * 16 + l16) * 64 + ((ks * 4 + quad) ^ xm) * 8);
                    #pragma unroll
                    for (int ni = 0; ni < 2; ni++)
                        b[ni] = *(const half8*)(Bb + (wn + ni * 16 + l16) * 64 + ((ks * 4 + quad) ^ xm) * 8);
                    #pragma unroll
                    for (int mi = 0; mi < 2; mi++)
                        #pragma unroll
                        for (int ni = 0; ni < 2; ni++)
                            acc[mi][ni] = __builtin_amdgcn_mfma_f32_16x16x32_f16(a[mi], b[ni], acc[mi][ni], 0, 0, 0);
                }
                if (more) CVW2(cur ^ 1);
                __syncthreads();
                cur ^= 1;
            }
            #undef LOAD2
            #undef CVW2

            #pragma unroll
            for (int mi = 0; mi < 2; mi++) {
                #pragma unroll
                for (int r = 0; r < 4; r++) {
                    int rr = wm + mi * 16 + quad * 4 + r;
                    if (rr >= cnt) continue;
                    size_t rowoff = ((size_t)kz * NP + row0 + rr) * D_;
                    #pragma unroll
                    for (int ni = 0; ni < 2; ni++)
                        p.Y2p[rowoff + colbase + wn + ni * 16 + l16] = acc[mi][ni][r];
                }
            }
        }
    }
    grid_sync();

    // ================= P4: combine + bias + LayerNorm (wave per token) =================
    {
        int wid = bid * 4 + wave;
        if (wid < NTOK) {
            int n = wid;
            int p0 = p.pos_of_pair[2 * n], p1 = p.pos_of_pair[2 * n + 1];
            int e0 = p.idx[2 * n], e1 = p.idx[2 * n + 1];
            float s0 = p.score[2 * n], s1 = p.score[2 * n + 1];

            const floatx4* b2r0 = (const floatx4*)(p.b2 + (size_t)e0 * D_);
            const floatx4* b2r1 = (const floatx4*)(p.b2 + (size_t)e1 * D_);
            floatx4 a_lo = b2r0[lane * 2], a_hi = b2r0[lane * 2 + 1];
            floatx4 c_lo = b2r1[lane * 2], c_hi = b2r1[lane * 2 + 1];
            #pragma unroll
            for (int kz = 0; kz < 4; kz++) {
                const floatx4* r0 = (const floatx4*)(p.Y2p + ((size_t)kz * NP + p0) * D_);
                const floatx4* r1 = (const floatx4*)(p.Y2p + ((size_t)kz * NP + p1) * D_);
                a_lo += r0[lane * 2]; a_hi += r0[lane * 2 + 1];
                c_lo += r1[lane * 2]; c_hi += r1[lane * 2 + 1];
            }
            floatx4 y_lo = s0 * a_lo + s1 * c_lo;
            floatx4 y_hi = s0 * a_hi + s1 * c_hi;

            float s = 0.0f, q = 0.0f;
            #pragma unroll
            for (int jj = 0; jj < 4; jj++) {
                s += y_lo[jj] + y_hi[jj];
                q += y_lo[jj] * y_lo[jj] + y_hi[jj] * y_hi[jj];
            }
            #pragma unroll
            for (int m = 1; m < 64; m <<= 1) {
                s += __shfl_xor(s, m);
                q += __shfl_xor(q, m);
            }
            float mean = s * (1.0f / 512.0f);
            float var = q * (1.0f / 512.0f) - mean * mean;
            float inv = 1.0f / sqrtf(var + 1e-5f);

            const floatx4* wv = (const floatx4*)p.ln_w;
            const floatx4* bv = (const floatx4*)p.ln_b;
            floatx4 o_lo = (y_lo - mean) * inv * wv[lane * 2]     + bv[lane * 2];
            floatx4 o_hi = (y_hi - mean) * inv * wv[lane * 2 + 1] + bv[lane * 2 + 1];
            floatx4* op = (floatx4*)(p.out + (size_t)n * D_);
            op[lane * 2] = o_lo;
            op[lane * 2 + 1] = o_hi;
        }
    }
}

extern "C" void kernel_launch(void* const* d_in, const int* in_sizes, int n_in,
                              void* d_out, int out_size, void* d_ws, size_t ws_size,
                              hipStream_t stream) {
    char* ws = (char*)d_ws;
    size_t o = 0;
    auto carve = [&](size_t bytes) -> char* {
        char* pc = ws + o;
        o += (bytes + 255) & ~(size_t)255;
        return pc;
    };
    half_t* Y1  = (half_t*)carve(sizeof(half_t) * (size_t)(NP + 128) * H_);
    float*  Y2p = (float*)carve(sizeof(float) * 4 * (size_t)NP * D_);
    float*  logits = (float*)carve(sizeof(float) * NTOK * E_);
    float*  score  = (float*)carve(sizeof(float) * NP);
    int* idx         = (int*)carve(sizeof(int) * NP);
    int* pos_of_pair = (int*)carve(sizeof(int) * NP);
    int* tok_of_pos  = (int*)carve(sizeof(int) * NP);
    int* tile_e      = (int*)carve(sizeof(int) * MAX_TILES);
    int* tile_row0   = (int*)carve(sizeof(int) * MAX_TILES);
    int* tile_cnt    = (int*)carve(sizeof(int) * MAX_TILES);
    int* ntiles      = (int*)carve(sizeof(int) * 1);

    KP hp;
    hp.inp    = (const float*)d_in[0];
    hp.gate_w = (const float*)d_in[1];
    hp.gate_b = (const float*)d_in[2];
    hp.w1     = (const float*)d_in[3];
    hp.b1     = (const float*)d_in[4];
    hp.w2     = (const float*)d_in[5];
    hp.b2     = (const float*)d_in[6];
    hp.ln_w   = (const float*)d_in[7];
    hp.ln_b   = (const float*)d_in[8];
    hp.out    = (float*)d_out;
    hp.Y1 = Y1; hp.Y2p = Y2p; hp.logits = logits; hp.score = score;
    hp.idx = idx; hp.pos_of_pair = pos_of_pair; hp.tok_of_pos = tok_of_pos;
    hp.tile_e = tile_e; hp.tile_row0 = tile_row0; hp.tile_cnt = tile_cnt;
    hp.ntiles = ntiles;

    void* kargs[] = { (void*)&hp };
    hipLaunchCooperativeKernel((const void*)moe_kernel, dim3(NBLK), dim3(256),
                               kargs, 0, stream);
}

// Round 5
// 269.185 us; speedup vs baseline: 2.5489x; 2.5489x over previous
//
#include <hip/hip_runtime.h>
#include <cstdint>
#include <cstddef>

typedef _Float16 half_t;
typedef _Float16 half8 __attribute__((ext_vector_type(8)));
typedef float floatx4 __attribute__((ext_vector_type(4)));

#define E_ 8
#define D_ 512
#define H_ 2048
#define NTOK 1024
#define NP 2048            // NTOK * top_k
#define TM 64              // GEMM M-tile rows
#define MAX_TILES 40       // 2048/64 + 8 experts

// ---- grid barrier state in device globals (monotonic gen; survives replays) ----
__device__ int g_cnt[8 * 32];   // per-XCD arrival counters, 128B apart
__device__ int g_xdone = 0;
__device__ int g_gen = 0;

// Two-level barrier. Arrive: RELEASE add on per-XCD line (one wbl2 per block).
// Wait: RELAXED spin (line-bypass load, NO cache invalidate per poll), then a
// single ACQUIRE fence. Round-4 version acquire-polled -> buffer_inv storm.
__device__ __forceinline__ void grid_sync(int xcd, int nb8) {
    __syncthreads();
    if (threadIdx.x == 0) {
        int g = __hip_atomic_load(&g_gen, __ATOMIC_RELAXED, __HIP_MEMORY_SCOPE_AGENT);
        int c = __hip_atomic_fetch_add(&g_cnt[xcd * 32], 1, __ATOMIC_ACQ_REL, __HIP_MEMORY_SCOPE_AGENT);
        if (c == nb8 - 1) {
            __hip_atomic_store(&g_cnt[xcd * 32], 0, __ATOMIC_RELAXED, __HIP_MEMORY_SCOPE_AGENT);
            int x = __hip_atomic_fetch_add(&g_xdone, 1, __ATOMIC_ACQ_REL, __HIP_MEMORY_SCOPE_AGENT);
            if (x == 7) {
                __hip_atomic_store(&g_xdone, 0, __ATOMIC_RELAXED, __HIP_MEMORY_SCOPE_AGENT);
                __hip_atomic_fetch_add(&g_gen, 1, __ATOMIC_RELEASE, __HIP_MEMORY_SCOPE_AGENT);
            }
        }
        while (__hip_atomic_load(&g_gen, __ATOMIC_RELAXED, __HIP_MEMORY_SCOPE_AGENT) == g)
            __builtin_amdgcn_s_sleep(8);
        __builtin_amdgcn_fence(__ATOMIC_ACQUIRE, "agent");
    }
    __syncthreads();
}

__device__ __forceinline__ float gelu_f(float x) {
    return 0.5f * x * (1.0f + erff(x * 0.7071067811865476f));
}

__device__ __forceinline__ half8 cvt8(floatx4 a, floatx4 b) {
    half8 h = { (half_t)a[0], (half_t)a[1], (half_t)a[2], (half_t)a[3],
                (half_t)b[0], (half_t)b[1], (half_t)b[2], (half_t)b[3] };
    return h;
}

struct KP {
    const float* inp; const float* gate_w; const float* gate_b;
    const float* w1; const float* b1; const float* w2; const float* b2;
    const float* ln_w; const float* ln_b; float* out;
    half_t* Y1; float* Y2p; float* logits; float* score;
    int* idx; int* pos_of_pair; int* tok_of_pos;
    int* tile_e; int* tile_row0; int* tile_cnt; int* ntiles;
    int nblk;
};

__global__ __launch_bounds__(256, 4) void moe_kernel(KP p) {
    __shared__ half_t As[2][64 * 64];   // 16 KB
    __shared__ half_t Bs[2][64 * 64];   // 16 KB
    __shared__ int cnt_s[E_], off_s[E_ + 1], cur_s[E_];
    const int bid = blockIdx.x, tid = threadIdx.x;
    const int wave = tid >> 6, lane = tid & 63;
    const int quad = lane >> 4, l16 = lane & 15;
    const int nb8 = p.nblk >> 3;
    const int xcd = bid & 7, ib = bid >> 3;

    // ================= P0: gate logits (wave per token) =================
    {
        int n = bid * 4 + wave;
        if (n < NTOK) {
            const floatx4* xr = (const floatx4*)(p.inp + (size_t)n * D_);
            floatx4 x0 = xr[lane * 2], x1 = xr[lane * 2 + 1];
            #pragma unroll
            for (int e = 0; e < E_; e++) {
                const floatx4* gr = (const floatx4*)(p.gate_w + (size_t)e * D_);
                floatx4 g0 = gr[lane * 2], g1 = gr[lane * 2 + 1];
                float v = x0[0]*g0[0] + x0[1]*g0[1] + x0[2]*g0[2] + x0[3]*g0[3]
                        + x1[0]*g1[0] + x1[1]*g1[1] + x1[2]*g1[2] + x1[3]*g1[3];
                #pragma unroll
                for (int m = 1; m < 64; m <<= 1) v += __shfl_xor(v, m);
                if (lane == 0) p.logits[(size_t)n * E_ + e] = v + p.gate_b[e];
            }
        }
    }
    grid_sync(xcd, nb8);

    // ================= P1: plan (block 0 only) =================
    if (bid == 0) {
        if (tid < E_) { cnt_s[tid] = 0; cur_s[tid] = 0; }
        __syncthreads();
        int my_e[4][2];
        #pragma unroll
        for (int i = 0; i < 4; i++) {
            int n = tid + i * 256;
            float l[E_];
            #pragma unroll
            for (int e = 0; e < E_; e++) l[e] = p.logits[(size_t)n * E_ + e];
            int e0 = 0; float v0 = l[0];
            #pragma unroll
            for (int e = 1; e < E_; e++) if (l[e] > v0) { v0 = l[e]; e0 = e; }
            int e1 = -1; float v1 = -3.4e38f;
            #pragma unroll
            for (int e = 0; e < E_; e++) if (e != e0 && l[e] > v1) { v1 = l[e]; e1 = e; }
            float s1 = expf(v1 - v0);
            float den = 1.0f + s1;
            p.score[2 * n]     = 1.0f / den;
            p.score[2 * n + 1] = s1 / den;
            p.idx[2 * n]     = e0;
            p.idx[2 * n + 1] = e1;
            atomicAdd(&cnt_s[e0], 1);
            atomicAdd(&cnt_s[e1], 1);
            my_e[i][0] = e0; my_e[i][1] = e1;
        }
        __syncthreads();
        if (tid == 0) {
            int o = 0;
            #pragma unroll
            for (int e = 0; e < E_; e++) { off_s[e] = o; o += cnt_s[e]; }
            off_s[E_] = o;
            int t = 0;
            for (int e = 0; e < E_; e++) {
                int c = cnt_s[e];
                int nt = (c + TM - 1) / TM;
                for (int i = 0; i < nt; i++) {
                    p.tile_e[t] = e;
                    p.tile_row0[t] = off_s[e] + i * TM;
                    int rem = c - i * TM;
                    p.tile_cnt[t] = rem < TM ? rem : TM;
                    t++;
                }
            }
            p.ntiles[0] = t;
        }
        __syncthreads();
        #pragma unroll
        for (int i = 0; i < 4; i++) {
            #pragma unroll
            for (int k = 0; k < 2; k++) {
                int pp = (tid + i * 256) * 2 + k;
                int e = my_e[i][k];
                int r = atomicAdd(&cur_s[e], 1);
                int pos = off_s[e] + r;
                p.pos_of_pair[pp] = pos;
                p.tok_of_pos[pos] = pp >> 1;
            }
        }
    }
    grid_sync(xcd, nb8);

    // shared geometry for the GEMM phases
    const int wm = (wave & 1) * 32, wn = (wave >> 1) * 32;
    const int xm = l16 & 7;
    const int gr0 = tid >> 3, gr1 = gr0 + 32, gc = tid & 7;
    const int sw0 = gc ^ (gr0 & 7), sw1 = gc ^ (gr1 & 7);
    const int sa0 = gr0 * 64 + sw0 * 8, sa1 = gr1 * 64 + sw1 * 8;

    // ================= P2: gemm1  Y1 = gelu(inp[tok] @ W1[e]^T + b1) =================
    // XCD x owns col-panels cb in {x, x+8, x+16, x+24}: w1 set = 4MB/XCD -> L2
    {
        const int nt = p.ntiles[0];
        for (int jj = ib; jj < 4 * MAX_TILES; jj += nb8) {
            int t = jj % MAX_TILES, cbi = jj / MAX_TILES;
            if (t >= nt) continue;
            int cb = xcd + cbi * 8;
            int e = p.tile_e[t], row0 = p.tile_row0[t], cnt = p.tile_cnt[t];
            int colbase = cb * 64;
            int ar0 = row0 + gr0; if (ar0 > NP - 1) ar0 = NP - 1;
            int ar1 = row0 + gr1; if (ar1 > NP - 1) ar1 = NP - 1;
            int tok0 = p.tok_of_pos[ar0];
            int tok1 = p.tok_of_pos[ar1];
            const floatx4* Ag0 = (const floatx4*)(p.inp + (size_t)tok0 * D_) + gc * 2;
            const floatx4* Ag1 = (const floatx4*)(p.inp + (size_t)tok1 * D_) + gc * 2;
            const floatx4* Bg0 = (const floatx4*)(p.w1 + ((size_t)e * H_ + colbase + gr0) * D_) + gc * 2;
            const floatx4* Bg1 = (const floatx4*)(p.w1 + ((size_t)e * H_ + colbase + gr1) * D_) + gc * 2;

            floatx4 ra0a, ra0b, ra1a, ra1b, rb0a, rb0b, rb1a, rb1b;
            #define LOAD1(kq) do { \
                ra0a = Ag0[kq]; ra0b = Ag0[(kq) + 1]; \
                ra1a = Ag1[kq]; ra1b = Ag1[(kq) + 1]; \
                rb0a = Bg0[kq]; rb0b = Bg0[(kq) + 1]; \
                rb1a = Bg1[kq]; rb1b = Bg1[(kq) + 1]; } while (0)
            #define CVW1(buf) do { \
                *(half8*)(&As[buf][sa0]) = cvt8(ra0a, ra0b); \
                *(half8*)(&As[buf][sa1]) = cvt8(ra1a, ra1b); \
                *(half8*)(&Bs[buf][sa0]) = cvt8(rb0a, rb0b); \
                *(half8*)(&Bs[buf][sa1]) = cvt8(rb1a, rb1b); } while (0)

            floatx4 acc[2][2] = {};
            LOAD1(0);
            CVW1(0);
            __syncthreads();
            int cur = 0;
            for (int k0 = 0; k0 < D_; k0 += 64) {
                bool more = (k0 + 64) < D_;
                if (more) LOAD1((k0 + 64) >> 2);
                const half_t* Ab = &As[cur][0];
                const half_t* Bb = &Bs[cur][0];
                #pragma unroll
                for (int ks = 0; ks < 2; ks++) {
                    half8 a[2], b[2];
                    #pragma unroll
                    for (int mi = 0; mi < 2; mi++)
                        a[mi] = *(const half8*)(Ab + (wm + mi * 16 + l16) * 64 + ((ks * 4 + quad) ^ xm) * 8);
                    #pragma unroll
                    for (int ni = 0; ni < 2; ni++)
                        b[ni] = *(const half8*)(Bb + (wn + ni * 16 + l16) * 64 + ((ks * 4 + quad) ^ xm) * 8);
                    #pragma unroll
                    for (int mi = 0; mi < 2; mi++)
                        #pragma unroll
                        for (int ni = 0; ni < 2; ni++)
                            acc[mi][ni] = __builtin_amdgcn_mfma_f32_16x16x32_f16(a[mi], b[ni], acc[mi][ni], 0, 0, 0);
                }
                if (more) CVW1(cur ^ 1);
                __syncthreads();
                cur ^= 1;
            }
            #undef LOAD1
            #undef CVW1

            float bias[2];
            #pragma unroll
            for (int ni = 0; ni < 2; ni++)
                bias[ni] = p.b1[(size_t)e * H_ + colbase + wn + ni * 16 + l16];
            #pragma unroll
            for (int mi = 0; mi < 2; mi++) {
                #pragma unroll
                for (int r = 0; r < 4; r++) {
                    int rr = wm + mi * 16 + quad * 4 + r;
                    if (rr >= cnt) continue;
                    size_t rowoff = (size_t)(row0 + rr) * H_;
                    #pragma unroll
                    for (int ni = 0; ni < 2; ni++) {
                        float v = acc[mi][ni][r] + bias[ni];
                        p.Y1[rowoff + colbase + wn + ni * 16 + l16] = (half_t)gelu_f(v);
                    }
                }
            }
        }
    }
    grid_sync(xcd, nb8);

    // ================= P3: gemm2 (split-K=4)  Y2p[kz] = Y1 @ W2[e]^T =================
    // XCD x owns output col-panel cb2 = x for all kz: w2 set = 4MB/XCD, read once
    {
        const int nt = p.ntiles[0];
        const int colbase = xcd * 64;
        for (int jj = ib; jj < 4 * MAX_TILES; jj += nb8) {
            int t = jj % MAX_TILES, kz = jj / MAX_TILES;
            if (t >= nt) continue;
            int e = p.tile_e[t], row0 = p.tile_row0[t], cnt = p.tile_cnt[t];
            int kzbase = kz * 512;
            const half8* Ag0 = (const half8*)(p.Y1 + (size_t)(row0 + gr0) * H_ + kzbase) + gc;
            const half8* Ag1 = (const half8*)(p.Y1 + (size_t)(row0 + gr1) * H_ + kzbase) + gc;
            const floatx4* Bg0 = (const floatx4*)(p.w2 + ((size_t)e * D_ + colbase + gr0) * H_ + kzbase) + gc * 2;
            const floatx4* Bg1 = (const floatx4*)(p.w2 + ((size_t)e * D_ + colbase + gr1) * H_ + kzbase) + gc * 2;

            half8 ha0, ha1;
            floatx4 rb0a, rb0b, rb1a, rb1b;
            #define LOAD2(k0) do { \
                ha0 = Ag0[(k0) >> 3]; ha1 = Ag1[(k0) >> 3]; \
                rb0a = Bg0[(k0) >> 2]; rb0b = Bg0[((k0) >> 2) + 1]; \
                rb1a = Bg1[(k0) >> 2]; rb1b = Bg1[((k0) >> 2) + 1]; } while (0)
            #define CVW2(buf) do { \
                *(half8*)(&As[buf][sa0]) = ha0; \
                *(half8*)(&As[buf][sa1]) = ha1; \
                *(half8*)(&Bs[buf][sa0]) = cvt8(rb0a, rb0b); \
                *(half8*)(&Bs[buf][sa1]) = cvt8(rb1a, rb1b); } while (0)

            floatx4 acc[2][2] = {};
            LOAD2(0);
            CVW2(0);
            __syncthreads();
            int cur = 0;
            for (int k0 = 0; k0 < 512; k0 += 64) {
                bool more = (k0 + 64) < 512;
                if (more) LOAD2(k0 + 64);
                const half_t* Ab = &As[cur][0];
                const half_t* Bb = &Bs[cur][0];
                #pragma unroll
                for (int ks = 0; ks < 2; ks++) {
                    half8 a[2], b[2];
                    #pragma unroll
                    for (int mi = 0; mi < 2; mi++)
                        a[mi] = *(const half8*)(Ab + (wm + mi * 16 + l16) * 64 + ((ks * 4 + quad) ^ xm) * 8);
                    #pragma unroll
                    for (int ni = 0; ni < 2; ni++)
                        b[ni] = *(const half8*)(Bb + (wn + ni * 16 + l16) * 64 + ((ks * 4 + quad) ^ xm) * 8);
                    #pragma unroll
                    for (int mi = 0; mi < 2; mi++)
                        #pragma unroll
                        for (int ni = 0; ni < 2; ni++)
                            acc[mi][ni] = __builtin_amdgcn_mfma_f32_16x16x32_f16(a[mi], b[ni], acc[mi][ni], 0, 0, 0);
                }
                if (more) CVW2(cur ^ 1);
                __syncthreads();
                cur ^= 1;
            }
            #undef LOAD2
            #undef CVW2

            #pragma unroll
            for (int mi = 0; mi < 2; mi++) {
                #pragma unroll
                for (int r = 0; r < 4; r++) {
                    int rr = wm + mi * 16 + quad * 4 + r;
                    if (rr >= cnt) continue;
                    size_t rowoff = ((size_t)kz * NP + row0 + rr) * D_;
                    #pragma unroll
                    for (int ni = 0; ni < 2; ni++)
                        p.Y2p[rowoff + colbase + wn + ni * 16 + l16] = acc[mi][ni][r];
                }
            }
        }
    }
    grid_sync(xcd, nb8);

    // ================= P4: combine + bias + LayerNorm (wave per token) =================
    {
        int n = bid * 4 + wave;
        if (n < NTOK) {
            int p0 = p.pos_of_pair[2 * n], p1 = p.pos_of_pair[2 * n + 1];
            int e0 = p.idx[2 * n], e1 = p.idx[2 * n + 1];
            float s0 = p.score[2 * n], s1 = p.score[2 * n + 1];

            const floatx4* b2r0 = (const floatx4*)(p.b2 + (size_t)e0 * D_);
            const floatx4* b2r1 = (const floatx4*)(p.b2 + (size_t)e1 * D_);
            floatx4 a_lo = b2r0[lane * 2], a_hi = b2r0[lane * 2 + 1];
            floatx4 c_lo = b2r1[lane * 2], c_hi = b2r1[lane * 2 + 1];
            #pragma unroll
            for (int kz = 0; kz < 4; kz++) {
                const floatx4* r0 = (const floatx4*)(p.Y2p + ((size_t)kz * NP + p0) * D_);
                const floatx4* r1 = (const floatx4*)(p.Y2p + ((size_t)kz * NP + p1) * D_);
                a_lo += r0[lane * 2]; a_hi += r0[lane * 2 + 1];
                c_lo += r1[lane * 2]; c_hi += r1[lane * 2 + 1];
            }
            floatx4 y_lo = s0 * a_lo + s1 * c_lo;
            floatx4 y_hi = s0 * a_hi + s1 * c_hi;

            float s = 0.0f, q = 0.0f;
            #pragma unroll
            for (int jj = 0; jj < 4; jj++) {
                s += y_lo[jj] + y_hi[jj];
                q += y_lo[jj] * y_lo[jj] + y_hi[jj] * y_hi[jj];
            }
            #pragma unroll
            for (int m = 1; m < 64; m <<= 1) {
                s += __shfl_xor(s, m);
                q += __shfl_xor(q, m);
            }
            float mean = s * (1.0f / 512.0f);
            float var = q * (1.0f / 512.0f) - mean * mean;
            float inv = 1.0f / sqrtf(var + 1e-5f);

            const floatx4* wv = (const floatx4*)p.ln_w;
            const floatx4* bv = (const floatx4*)p.ln_b;
            floatx4 o_lo = (y_lo - mean) * inv * wv[lane * 2]     + bv[lane * 2];
            floatx4 o_hi = (y_hi - mean) * inv * wv[lane * 2 + 1] + bv[lane * 2 + 1];
            floatx4* op = (floatx4*)(p.out + (size_t)n * D_);
            op[lane * 2] = o_lo;
            op[lane * 2 + 1] = o_hi;
        }
    }
}

extern "C" void kernel_launch(void* const* d_in, const int* in_sizes, int n_in,
                              void* d_out, int out_size, void* d_ws, size_t ws_size,
                              hipStream_t stream) {
    char* ws = (char*)d_ws;
    size_t o = 0;
    auto carve = [&](size_t bytes) -> char* {
        char* pc = ws + o;
        o += (bytes + 255) & ~(size_t)255;
        return pc;
    };
    half_t* Y1  = (half_t*)carve(sizeof(half_t) * (size_t)(NP + 128) * H_);
    float*  Y2p = (float*)carve(sizeof(float) * 4 * (size_t)NP * D_);
    float*  logits = (float*)carve(sizeof(float) * NTOK * E_);
    float*  score  = (float*)carve(sizeof(float) * NP);
    int* idx         = (int*)carve(sizeof(int) * NP);
    int* pos_of_pair = (int*)carve(sizeof(int) * NP);
    int* tok_of_pos  = (int*)carve(sizeof(int) * NP);
    int* tile_e      = (int*)carve(sizeof(int) * MAX_TILES);
    int* tile_row0   = (int*)carve(sizeof(int) * MAX_TILES);
    int* tile_cnt    = (int*)carve(sizeof(int) * MAX_TILES);
    int* ntiles      = (int*)carve(sizeof(int) * 1);

    KP hp;
    hp.inp    = (const float*)d_in[0];
    hp.gate_w = (const float*)d_in[1];
    hp.gate_b = (const float*)d_in[2];
    hp.w1     = (const float*)d_in[3];
    hp.b1     = (const float*)d_in[4];
    hp.w2     = (const float*)d_in[5];
    hp.b2     = (const float*)d_in[6];
    hp.ln_w   = (const float*)d_in[7];
    hp.ln_b   = (const float*)d_in[8];
    hp.out    = (float*)d_out;
    hp.Y1 = Y1; hp.Y2p = Y2p; hp.logits = logits; hp.score = score;
    hp.idx = idx; hp.pos_of_pair = pos_of_pair; hp.tok_of_pos = tok_of_pos;
    hp.tile_e = tile_e; hp.tile_row0 = tile_row0; hp.tile_cnt = tile_cnt;
    hp.ntiles = ntiles;

    int bpc = 0;
    if (hipOccupancyMaxActiveBlocksPerMultiprocessor(&bpc, moe_kernel, 256, 0) != hipSuccess)
        bpc = 2;
    int nblk = bpc * 256;
    if (nblk > 1024) nblk = 1024;
    if (nblk < 512) nblk = 512;
    hp.nblk = nblk;

    void* kargs[] = { (void*)&hp };
    hipLaunchCooperativeKernel((const void*)moe_kernel, dim3(nblk), dim3(256),
                               kargs, 0, stream);
}

// Round 7
// 177.137 us; speedup vs baseline: 3.8734x; 1.5196x over previous
//
#include <hip/hip_runtime.h>
#include <cstdint>
#include <cstddef>

typedef _Float16 half_t;
typedef _Float16 half8 __attribute__((ext_vector_type(8)));
typedef float floatx4 __attribute__((ext_vector_type(4)));

#define E_ 8
#define D_ 512
#define H_ 2048
#define NTOK 1024
#define NP 2048            // NTOK * top_k
#define TM 64              // GEMM M-tile rows
#define MAX_TILES 40       // 2048/64 + 8 experts

__device__ __forceinline__ float gelu_f(float x) {
    return 0.5f * x * (1.0f + erff(x * 0.7071067811865476f));
}

__device__ __forceinline__ half8 cvt8(floatx4 a, floatx4 b) {
    half8 h = { (half_t)a[0], (half_t)a[1], (half_t)a[2], (half_t)a[3],
                (half_t)b[0], (half_t)b[1], (half_t)b[2], (half_t)b[3] };
    return h;
}

// ---------------- gate: logits only ----------------
__global__ __launch_bounds__(256) void gate_kernel(
        const float* __restrict__ inp, const float* __restrict__ gate_w,
        const float* __restrict__ gate_b, float* __restrict__ logits) {
    int n = blockIdx.x * 4 + (threadIdx.x >> 6);
    int lane = threadIdx.x & 63;
    const floatx4* xr = (const floatx4*)(inp + (size_t)n * D_);
    floatx4 x0 = xr[lane * 2], x1 = xr[lane * 2 + 1];
    #pragma unroll
    for (int e = 0; e < E_; e++) {
        const floatx4* gr = (const floatx4*)(gate_w + (size_t)e * D_);
        floatx4 g0 = gr[lane * 2], g1 = gr[lane * 2 + 1];
        float p = x0[0]*g0[0] + x0[1]*g0[1] + x0[2]*g0[2] + x0[3]*g0[3]
                + x1[0]*g1[0] + x1[1]*g1[1] + x1[2]*g1[2] + x1[3]*g1[3];
        #pragma unroll
        for (int m = 1; m < 64; m <<= 1) p += __shfl_xor(p, m);
        if (lane == 0) logits[(size_t)n * E_ + e] = p + gate_b[e];
    }
}

// ---------------- plan: top2/softmax/hist/offsets/tiles/pos maps ----------------
__global__ __launch_bounds__(256) void plan_kernel(
        const float* __restrict__ logits, float* __restrict__ score,
        int* __restrict__ idx, int* __restrict__ pos_of_pair,
        int* __restrict__ tok_of_pos,
        int* __restrict__ tile_e, int* __restrict__ tile_row0,
        int* __restrict__ tile_cnt, int* __restrict__ ntiles) {
    __shared__ int cnt_s[E_], off_s[E_ + 1], cur_s[E_];
    int tid = threadIdx.x;
    if (tid < E_) { cnt_s[tid] = 0; cur_s[tid] = 0; }
    __syncthreads();
    int my_e[4][2];
    #pragma unroll
    for (int i = 0; i < 4; i++) {
        int n = tid + i * 256;
        float l[E_];
        #pragma unroll
        for (int e = 0; e < E_; e++) l[e] = logits[(size_t)n * E_ + e];
        int e0 = 0; float v0 = l[0];
        #pragma unroll
        for (int e = 1; e < E_; e++) if (l[e] > v0) { v0 = l[e]; e0 = e; }
        int e1 = -1; float v1 = -3.4e38f;
        #pragma unroll
        for (int e = 0; e < E_; e++) if (e != e0 && l[e] > v1) { v1 = l[e]; e1 = e; }
        float s1 = expf(v1 - v0);
        float den = 1.0f + s1;
        score[2 * n]     = 1.0f / den;
        score[2 * n + 1] = s1 / den;
        idx[2 * n]     = e0;
        idx[2 * n + 1] = e1;
        atomicAdd(&cnt_s[e0], 1);
        atomicAdd(&cnt_s[e1], 1);
        my_e[i][0] = e0; my_e[i][1] = e1;
    }
    __syncthreads();
    if (tid == 0) {
        int o = 0;
        #pragma unroll
        for (int e = 0; e < E_; e++) { off_s[e] = o; o += cnt_s[e]; }
        off_s[E_] = o;
        int t = 0;
        for (int e = 0; e < E_; e++) {
            int c = cnt_s[e];
            int nt = (c + TM - 1) / TM;
            for (int i = 0; i < nt; i++) {
                tile_e[t] = e;
                tile_row0[t] = off_s[e] + i * TM;
                int rem = c - i * TM;
                tile_cnt[t] = rem < TM ? rem : TM;
                t++;
            }
        }
        ntiles[0] = t;
    }
    __syncthreads();
    #pragma unroll
    for (int i = 0; i < 4; i++) {
        #pragma unroll
        for (int k = 0; k < 2; k++) {
            int pp = (tid + i * 256) * 2 + k;
            int e = my_e[i][k];
            int r = atomicAdd(&cur_s[e], 1);
            int pos = off_s[e] + r;
            pos_of_pair[pp] = pos;
            tok_of_pos[pos] = pp >> 1;
        }
    }
}

// ---------------- GEMM1: Y1 = gelu(inp[tok] @ W1[e]^T + b1[e]) ----------------
// Weight-stationary: full B panel (64 H-cols x 512 K) staged f32->f16 in LDS once
// (burst of 16 deep loads/thread), then 8 K-iters with tiny A double-buffer.
// XCD x owns col-panels {4x .. 4x+3}: w1 slab 4 MB/XCD = L2-resident re-reads.
__global__ __launch_bounds__(256) void gemm1_kernel(
        const float* __restrict__ inp, const int* __restrict__ tok_of_pos,
        const float* __restrict__ w1, const float* __restrict__ b1,
        const int* __restrict__ tile_e, const int* __restrict__ tile_row0,
        const int* __restrict__ tile_cnt, const int* __restrict__ ntiles,
        half_t* __restrict__ Y1) {
    __shared__ half_t Bs[64 * 512];     // 64 KB
    __shared__ half_t As[2][64 * 64];   // 16 KB
    const int bid = blockIdx.x, tid = threadIdx.x;
    const int xcd = bid & 7, ib = bid >> 3;     // 160 jobs per XCD
    const int t = ib % MAX_TILES;
    const int cb = xcd * 4 + ib / MAX_TILES;    // 4 consecutive panels per XCD
    if (t >= ntiles[0]) return;
    const int e = tile_e[t], row0 = tile_row0[t], cnt = tile_cnt[t];
    const int colbase = cb * 64;
    const int wave = tid >> 6, lane = tid & 63;
    const int quad = lane >> 4, l16 = lane & 15;
    const int wm = (wave & 1) * 32, wn = (wave >> 1) * 32;
    const int xm = l16 & 7;

    // ---- A staging geometry (proven round-3/5 machinery) ----
    const int gr0 = tid >> 3, gr1 = gr0 + 32, gc = tid & 7;
    const int sw0 = gc ^ (gr0 & 7), sw1 = gc ^ (gr1 & 7);
    const int sa0 = gr0 * 64 + sw0 * 8, sa1 = gr1 * 64 + sw1 * 8;
    int ar0 = row0 + gr0; if (ar0 > NP - 1) ar0 = NP - 1;
    int ar1 = row0 + gr1; if (ar1 > NP - 1) ar1 = NP - 1;
    const floatx4* Ag0 = (const floatx4*)(inp + (size_t)tok_of_pos[ar0] * D_) + gc * 2;
    const floatx4* Ag1 = (const floatx4*)(inp + (size_t)tok_of_pos[ar1] * D_) + gc * 2;

    floatx4 ra0a, ra0b, ra1a, ra1b;
    #define LOADA(kq) do { \
        ra0a = Ag0[kq]; ra0b = Ag0[(kq) + 1]; \
        ra1a = Ag1[kq]; ra1b = Ag1[(kq) + 1]; } while (0)
    #define CVWA(buf) do { \
        *(half8*)(&As[buf][sa0]) = cvt8(ra0a, ra0b); \
        *(half8*)(&As[buf][sa1]) = cvt8(ra1a, ra1b); } while (0)

    LOADA(0);   // issue first A chunk before the B burst

    // ---- stage full B panel: 4096 granules of 8 floats, octet-XOR swizzle ----
    #pragma unroll
    for (int hb = 0; hb < 2; hb++) {
        floatx4 v0[8], v1[8];
        #pragma unroll
        for (int u = 0; u < 8; u++) {
            int gid = tid + (hb * 8 + u) * 256;
            int row = gid >> 6, g = gid & 63;
            const floatx4* src = (const floatx4*)(w1 + ((size_t)e * H_ + colbase + row) * D_ + g * 8);
            v0[u] = src[0]; v1[u] = src[1];
        }
        #pragma unroll
        for (int u = 0; u < 8; u++) {
            int gid = tid + (hb * 8 + u) * 256;
            int row = gid >> 6, g = gid & 63;
            int gs = (g & 56) | ((g ^ row) & 7);
            *(half8*)(&Bs[row * 512 + gs * 8]) = cvt8(v0[u], v1[u]);
        }
    }
    CVWA(0);
    __syncthreads();    // Bs + As[0] ready

    floatx4 acc[2][2] = {};
    int cur = 0;
    for (int k0 = 0; k0 < D_; k0 += 64) {
        bool more = (k0 + 64) < D_;
        if (more) LOADA((k0 + 64) >> 2);
        const half_t* Ab = &As[cur][0];
        const int kg0 = k0 >> 3;
        #pragma unroll
        for (int ks = 0; ks < 2; ks++) {
            half8 a[2], b[2];
            #pragma unroll
            for (int mi = 0; mi < 2; mi++)
                a[mi] = *(const half8*)(Ab + (wm + mi * 16 + l16) * 64 + ((ks * 4 + quad) ^ xm) * 8);
            #pragma unroll
            for (int ni = 0; ni < 2; ni++)
                b[ni] = *(const half8*)(&Bs[(wn + ni * 16 + l16) * 512 + (kg0 + ((ks * 4 + quad) ^ xm)) * 8]);
            #pragma unroll
            for (int mi = 0; mi < 2; mi++)
                #pragma unroll
                for (int ni = 0; ni < 2; ni++)
                    acc[mi][ni] = __builtin_amdgcn_mfma_f32_16x16x32_f16(a[mi], b[ni], acc[mi][ni], 0, 0, 0);
        }
        if (more) CVWA(cur ^ 1);
        __syncthreads();
        cur ^= 1;
    }
    #undef LOADA
    #undef CVWA

    float bias[2];
    #pragma unroll
    for (int ni = 0; ni < 2; ni++)
        bias[ni] = b1[(size_t)e * H_ + colbase + wn + ni * 16 + l16];
    #pragma unroll
    for (int mi = 0; mi < 2; mi++) {
        #pragma unroll
        for (int r = 0; r < 4; r++) {
            int rr = wm + mi * 16 + quad * 4 + r;
            if (rr >= cnt) continue;
            size_t rowoff = (size_t)(row0 + rr) * H_;
            #pragma unroll
            for (int ni = 0; ni < 2; ni++) {
                float v = acc[mi][ni][r] + bias[ni];
                Y1[rowoff + colbase + wn + ni * 16 + l16] = (half_t)gelu_f(v);
            }
        }
    }
}

// ---------------- GEMM2 (split-K=4): Y2p[kz] = Y1 @ W2[e]^T ----------------
// Same weight-stationary structure; XCD x owns D-col panel x (all kz):
// w2 slab 4 MB/XCD = L2-resident re-reads across tiles.
__global__ __launch_bounds__(256) void gemm2_kernel(
        const half_t* __restrict__ Y1, const float* __restrict__ w2,
        const int* __restrict__ tile_e, const int* __restrict__ tile_row0,
        const int* __restrict__ tile_cnt, const int* __restrict__ ntiles,
        float* __restrict__ Y2p) {
    __shared__ half_t Bs[64 * 512];     // 64 KB
    __shared__ half_t As[2][64 * 64];   // 16 KB
    const int bid = blockIdx.x, tid = threadIdx.x;
    const int xcd = bid & 7, ib = bid >> 3;     // 160 jobs per XCD
    const int t = ib % MAX_TILES;
    const int kz = ib / MAX_TILES;              // 4 kz slabs per XCD
    if (t >= ntiles[0]) return;
    const int e = tile_e[t], row0 = tile_row0[t], cnt = tile_cnt[t];
    const int colbase = xcd * 64;               // XCD owns its D-col panel
    const int kzbase = kz * 512;
    const int wave = tid >> 6, lane = tid & 63;
    const int quad = lane >> 4, l16 = lane & 15;
    const int wm = (wave & 1) * 32, wn = (wave >> 1) * 32;
    const int xm = l16 & 7;

    const int gr0 = tid >> 3, gr1 = gr0 + 32, gc = tid & 7;
    const int sw0 = gc ^ (gr0 & 7), sw1 = gc ^ (gr1 & 7);
    const int sa0 = gr0 * 64 + sw0 * 8, sa1 = gr1 * 64 + sw1 * 8;
    const half8* Ag0 = (const half8*)(Y1 + (size_t)(row0 + gr0) * H_ + kzbase) + gc;
    const half8* Ag1 = (const half8*)(Y1 + (size_t)(row0 + gr1) * H_ + kzbase) + gc;

    half8 ha0, ha1;
    #define LOADA2(k0) do { \
        ha0 = Ag0[(k0) >> 3]; ha1 = Ag1[(k0) >> 3]; } while (0)
    #define CVWA2(buf) do { \
        *(half8*)(&As[buf][sa0]) = ha0; \
        *(half8*)(&As[buf][sa1]) = ha1; } while (0)

    LOADA2(0);

    // ---- stage full B slab: w2[e], 64 D-cols x 512 K (kz slice) ----
    #pragma unroll
    for (int hb = 0; hb < 2; hb++) {
        floatx4 v0[8], v1[8];
        #pragma unroll
        for (int u = 0; u < 8; u++) {
            int gid = tid + (hb * 8 + u) * 256;
            int row = gid >> 6, g = gid & 63;
            const floatx4* src = (const floatx4*)(w2 + ((size_t)e * D_ + colbase + row) * H_ + kzbase + g * 8);
            v0[u] = src[0]; v1[u] = src[1];
        }
        #pragma unroll
        for (int u = 0; u < 8; u++) {
            int gid = tid + (hb * 8 + u) * 256;
            int row = gid >> 6, g = gid & 63;
            int gs = (g & 56) | ((g ^ row) & 7);
            *(half8*)(&Bs[row * 512 + gs * 8]) = cvt8(v0[u], v1[u]);
        }
    }
    CVWA2(0);
    __syncthreads();

    floatx4 acc[2][2] = {};
    int cur = 0;
    for (int k0 = 0; k0 < 512; k0 += 64) {
        bool more = (k0 + 64) < 512;
        if (more) LOADA2(k0 + 64);
        const half_t* Ab = &As[cur][0];
        const int kg0 = k0 >> 3;
        #pragma unroll
        for (int ks = 0; ks < 2; ks++) {
            half8 a[2], b[2];
            #pragma unroll
            for (int mi = 0; mi < 2; mi++)
                a[mi] = *(const half8*)(Ab + (wm + mi * 16 + l16) * 64 + ((ks * 4 + quad) ^ xm) * 8);
            #pragma unroll
            for (int ni = 0; ni < 2; ni++)
                b[ni] = *(const half8*)(&Bs[(wn + ni * 16 + l16) * 512 + (kg0 + ((ks * 4 + quad) ^ xm)) * 8]);
            #pragma unroll
            for (int mi = 0; mi < 2; mi++)
                #pragma unroll
                for (int ni = 0; ni < 2; ni++)
                    acc[mi][ni] = __builtin_amdgcn_mfma_f32_16x16x32_f16(a[mi], b[ni], acc[mi][ni], 0, 0, 0);
        }
        if (more) CVWA2(cur ^ 1);
        __syncthreads();
        cur ^= 1;
    }
    #undef LOADA2
    #undef CVWA2

    #pragma unroll
    for (int mi = 0; mi < 2; mi++) {
        #pragma unroll
        for (int r = 0; r < 4; r++) {
            int rr = wm + mi * 16 + quad * 4 + r;
            if (rr >= cnt) continue;
            size_t rowoff = ((size_t)kz * NP + row0 + rr) * D_;
            #pragma unroll
            for (int ni = 0; ni < 2; ni++)
                Y2p[rowoff + colbase + wn + ni * 16 + l16] = acc[mi][ni][r];
        }
    }
}

// ---------------- combine + bias + LayerNorm, wave per token ----------------
__global__ __launch_bounds__(256) void final_kernel(
        const float* __restrict__ Y2p, const float* __restrict__ b2,
        const int* __restrict__ idx, const float* __restrict__ score,
        const int* __restrict__ pos_of_pair,
        const float* __restrict__ ln_w, const float* __restrict__ ln_b,
        float* __restrict__ out) {
    int n = blockIdx.x * 4 + (threadIdx.x >> 6);
    int lane = threadIdx.x & 63;
    int p0 = pos_of_pair[2 * n], p1 = pos_of_pair[2 * n + 1];
    int e0 = idx[2 * n], e1 = idx[2 * n + 1];
    float s0 = score[2 * n], s1 = score[2 * n + 1];

    const floatx4* b2r0 = (const floatx4*)(b2 + (size_t)e0 * D_);
    const floatx4* b2r1 = (const floatx4*)(b2 + (size_t)e1 * D_);
    floatx4 a_lo = b2r0[lane * 2], a_hi = b2r0[lane * 2 + 1];
    floatx4 c_lo = b2r1[lane * 2], c_hi = b2r1[lane * 2 + 1];
    #pragma unroll
    for (int kz = 0; kz < 4; kz++) {
        const floatx4* r0 = (const floatx4*)(Y2p + ((size_t)kz * NP + p0) * D_);
        const floatx4* r1 = (const floatx4*)(Y2p + ((size_t)kz * NP + p1) * D_);
        a_lo += r0[lane * 2]; a_hi += r0[lane * 2 + 1];
        c_lo += r1[lane * 2]; c_hi += r1[lane * 2 + 1];
    }
    floatx4 y_lo = s0 * a_lo + s1 * c_lo;
    floatx4 y_hi = s0 * a_hi + s1 * c_hi;

    float s = 0.0f, q = 0.0f;
    #pragma unroll
    for (int j = 0; j < 4; j++) {
        s += y_lo[j] + y_hi[j];
        q += y_lo[j] * y_lo[j] + y_hi[j] * y_hi[j];
    }
    #pragma unroll
    for (int m = 1; m < 64; m <<= 1) {
        s += __shfl_xor(s, m);
        q += __shfl_xor(q, m);
    }
    float mean = s * (1.0f / 512.0f);
    float var = q * (1.0f / 512.0f) - mean * mean;
    float inv = 1.0f / sqrtf(var + 1e-5f);

    const floatx4* wv = (const floatx4*)ln_w;
    const floatx4* bv = (const floatx4*)ln_b;
    floatx4 o_lo = (y_lo - mean) * inv * wv[lane * 2]     + bv[lane * 2];
    floatx4 o_hi = (y_hi - mean) * inv * wv[lane * 2 + 1] + bv[lane * 2 + 1];
    floatx4* op = (floatx4*)(out + (size_t)n * D_);
    op[lane * 2] = o_lo;
    op[lane * 2 + 1] = o_hi;
}

extern "C" void kernel_launch(void* const* d_in, const int* in_sizes, int n_in,
                              void* d_out, int out_size, void* d_ws, size_t ws_size,
                              hipStream_t stream) {
    const float* inp    = (const float*)d_in[0];
    const float* gate_w = (const float*)d_in[1];
    const float* gate_b = (const float*)d_in[2];
    const float* w1     = (const float*)d_in[3];
    const float* b1     = (const float*)d_in[4];
    const float* w2     = (const float*)d_in[5];
    const float* b2     = (const float*)d_in[6];
    const float* ln_w   = (const float*)d_in[7];
    const float* ln_b   = (const float*)d_in[8];
    float* out = (float*)d_out;

    char* ws = (char*)d_ws;
    size_t o = 0;
    auto carve = [&](size_t bytes) -> char* {
        char* p = ws + o;
        o += (bytes + 255) & ~(size_t)255;
        return p;
    };
    half_t* Y1  = (half_t*)carve(sizeof(half_t) * (size_t)(NP + 128) * H_);  // slack rows
    float*  Y2p = (float*)carve(sizeof(float) * 4 * (size_t)NP * D_);
    float*  logits = (float*)carve(sizeof(float) * NTOK * E_);
    float*  score  = (float*)carve(sizeof(float) * NP);
    int* idx         = (int*)carve(sizeof(int) * NP);
    int* pos_of_pair = (int*)carve(sizeof(int) * NP);
    int* tok_of_pos  = (int*)carve(sizeof(int) * NP);
    int* tile_e      = (int*)carve(sizeof(int) * MAX_TILES);
    int* tile_row0   = (int*)carve(sizeof(int) * MAX_TILES);
    int* tile_cnt    = (int*)carve(sizeof(int) * MAX_TILES);
    int* ntiles      = (int*)carve(sizeof(int) * 1);

    gate_kernel<<<NTOK / 4, 256, 0, stream>>>(inp, gate_w, gate_b, logits);
    plan_kernel<<<1, 256, 0, stream>>>(logits, score, idx, pos_of_pair, tok_of_pos,
                                       tile_e, tile_row0, tile_cnt, ntiles);
    // 1280 jobs each: 8 XCD chunks x (40 tiles x 4 panels/kz)
    gemm1_kernel<<<MAX_TILES * 32, 256, 0, stream>>>(
        inp, tok_of_pos, w1, b1, tile_e, tile_row0, tile_cnt, ntiles, Y1);
    gemm2_kernel<<<MAX_TILES * 32, 256, 0, stream>>>(
        Y1, w2, tile_e, tile_row0, tile_cnt, ntiles, Y2p);
    final_kernel<<<NTOK / 4, 256, 0, stream>>>(Y2p, b2, idx, score, pos_of_pair, ln_w, ln_b, out);
}